// Round 1
// baseline (173.226 us; speedup 1.0000x reference)
//
#include <hip/hip_runtime.h>
#include <hip/hip_bf16.h>
#include <math.h>

#define B   64
#define L1  199
#define L   200
#define NC  1000
#define D   64
#define M   50
#define NCH 5      // m-chunks in the scan (M/MC)
#define MC  10     // m per chunk
#define TC  20     // time-chunk staged into LDS in the scan

__device__ __forceinline__ float readlane_f(float v, int lane) {
    return __uint_as_float(__builtin_amdgcn_readlane(__float_as_uint(v), lane));
}

// ---------------- Phase 1: w = softmax(k@Mk^T), e = sigmoid(v@We+be), a = tanh(v@Wa+ba)
// grid 800 x 256 ; block = 4 waves, each wave processes 4 positions
__global__ __launch_bounds__(256) void phase1(
    const int* __restrict__ cseqs, const int* __restrict__ rseqs,
    const int* __restrict__ shft_cseqs, const int* __restrict__ shft_rseqs,
    const float* __restrict__ kemb, const float* __restrict__ vemb,
    const float* __restrict__ Mk, const float* __restrict__ We,
    const float* __restrict__ be, const float* __restrict__ Wa,
    const float* __restrict__ ba,
    float* __restrict__ w_out, float* __restrict__ e_out, float* __restrict__ a_out)
{
    __shared__ float smem[50 * 65 + 64 * 64 + 64 * 64];
    float* Mk_s = smem;             // [50][65]  (+1 pad: lane=m reads stride-65 -> conflict-free)
    float* We_s = smem + 50 * 65;   // [64][64]  (lane=d_out reads column: 2-way alias = free)
    float* Wa_s = We_s + 64 * 64;

    const int tid = threadIdx.x;
    for (int i = tid; i < 3200; i += 256)
        Mk_s[(i >> 6) * 65 + (i & 63)] = Mk[i];
    {
        const float4* s1 = (const float4*)We;
        const float4* s2 = (const float4*)Wa;
        float4* d1 = (float4*)We_s;
        float4* d2 = (float4*)Wa_s;
        for (int i = tid; i < 1024; i += 256) { d1[i] = s1[i]; d2[i] = s2[i]; }
    }
    __syncthreads();

    const int lane = tid & 63;
    const int wave = tid >> 6;
    const float be_r = be[lane];
    const float ba_r = ba[lane];

    for (int p = 0; p < 4; ++p) {
        const int gpos = blockIdx.x * 16 + wave * 4 + p;   // 800*16 = 12800 = B*L exactly
        const int b = gpos / L, l = gpos % L;
        int q, r;
        if (l == 0) { q = cseqs[b * L1];         r = rseqs[b * L1]; }
        else        { q = shft_cseqs[b * L1 + l - 1]; r = shft_rseqs[b * L1 + l - 1]; }
        const int x = q + NC * r;
        const float kd = kemb[q * D + lane];
        const float vd = vemb[x * D + lane];

        // logits over m (lane = m); k[d] broadcast via readlane
        float acc = 0.f;
        #pragma unroll
        for (int d = 0; d < D; ++d)
            acc = fmaf(Mk_s[lane * 65 + d], readlane_f(kd, d), acc);
        float logit = (lane < M) ? acc : -INFINITY;
        float mx = logit;
        #pragma unroll
        for (int off = 32; off; off >>= 1) mx = fmaxf(mx, __shfl_xor(mx, off, 64));
        const float ex = expf(logit - mx);
        float sm = ex;
        #pragma unroll
        for (int off = 32; off; off >>= 1) sm += __shfl_xor(sm, off, 64);
        if (lane < M) w_out[gpos * M + lane] = ex / sm;

        // e, a (lane = d_out); v[d_in] broadcast via readlane
        float acce = 0.f, acca = 0.f;
        #pragma unroll
        for (int din = 0; din < D; ++din) {
            const float sv = readlane_f(vd, din);
            acce = fmaf(We_s[din * D + lane], sv, acce);
            acca = fmaf(Wa_s[din * D + lane], sv, acca);
        }
        e_out[gpos * D + lane] = 1.f / (1.f + expf(-(acce + be_r)));
        a_out[gpos * D + lane] = tanhf(acca + ba_r);
    }
}

// ---------------- Phase 2: the scan. One single-wave block per (b, m-chunk).
// lane = d; each lane carries Mv[MC] in registers. Partial reads written per step.
__global__ __launch_bounds__(64) void phase2(
    const float* __restrict__ Mv0,
    const float* __restrict__ w_in, const float* __restrict__ e_in,
    const float* __restrict__ a_in, float* __restrict__ rp_out)
{
    __shared__ float es[TC * D];
    __shared__ float as_[TC * D];
    __shared__ float wss[TC * M];
    const int lane = threadIdx.x;
    const int b  = blockIdx.x / NCH;
    const int ch = blockIdx.x % NCH;
    const int m0 = ch * MC;

    float Mv[MC];
    #pragma unroll
    for (int j = 0; j < MC; ++j) Mv[j] = Mv0[(m0 + j) * D + lane];

    for (int tcb = 0; tcb < L / TC; ++tcb) {
        const int t0 = tcb * TC;
        // stage this time-chunk's e/a/w into LDS (bulk, coalesced)
        {
            const float4* se = (const float4*)(e_in + (size_t)(b * L + t0) * D);
            const float4* sa = (const float4*)(a_in + (size_t)(b * L + t0) * D);
            float4* de = (float4*)es;
            float4* da = (float4*)as_;
            #pragma unroll
            for (int i = 0; i < (TC * D / 4) / 64; ++i) {   // 5 iters
                de[lane + 64 * i] = se[lane + 64 * i];
                da[lane + 64 * i] = sa[lane + 64 * i];
            }
            const float* sw = w_in + (size_t)(b * L + t0) * M;
            for (int i = lane; i < TC * M; i += 64) wss[i] = sw[i];
        }
        __syncthreads();
        for (int t = 0; t < TC; ++t) {
            const float ed = es[t * D + lane];
            const float ad = as_[t * D + lane];
            float racc = 0.f;
            #pragma unroll
            for (int j = 0; j < MC; ++j) {
                const float wm = wss[t * M + m0 + j];       // uniform addr -> broadcast
                racc = fmaf(wm, Mv[j], racc);               // read BEFORE update
                const float we = wm * ed;
                Mv[j] = fmaf(Mv[j], -we, fmaf(wm, ad, Mv[j]));  // Mv*(1-we)+wm*ad
            }
            rp_out[(((size_t)ch * B + b) * L + t0 + t) * D + lane] = racc;
        }
        __syncthreads();
    }
}

// ---------------- Phase 3: read = sum of partials; f = tanh([read,k]@Wf+bf); p = sigmoid(f@Wp+bp)
// grid 800 x 512 ; block = 8 waves x 2 positions
__global__ __launch_bounds__(512) void phase3(
    const int* __restrict__ cseqs, const int* __restrict__ shft_cseqs,
    const float* __restrict__ kemb,
    const float* __restrict__ Wf, const float* __restrict__ bf,
    const float* __restrict__ Wp, const float* __restrict__ bp,
    const float* __restrict__ rp, float* __restrict__ out)
{
    __shared__ float Wf_s[128 * 64];
    const int tid = threadIdx.x;
    {
        const float4* s = (const float4*)Wf;
        float4* d4 = (float4*)Wf_s;
        for (int i = tid; i < 2048; i += 512) d4[i] = s[i];
    }
    __syncthreads();
    const int lane = tid & 63;
    const int wave = tid >> 6;
    const float bf_r = bf[lane];
    const float wp_r = Wp[lane];
    const float bp_r = bp[0];

    for (int p = 0; p < 2; ++p) {
        const int gpos = blockIdx.x * 16 + wave * 2 + p;   // 800*16 = 12800
        const int b = gpos / L, l = gpos % L;
        float rd = 0.f;
        #pragma unroll
        for (int ch = 0; ch < NCH; ++ch)
            rd += rp[(((size_t)ch * B + b) * L + l) * D + lane];
        const int q = (l == 0) ? cseqs[b * L1] : shft_cseqs[b * L1 + l - 1];
        const float kd = kemb[q * D + lane];

        float facc = 0.f;
        #pragma unroll
        for (int i = 0; i < D; ++i)
            facc = fmaf(Wf_s[i * D + lane], readlane_f(rd, i), facc);
        #pragma unroll
        for (int i = 0; i < D; ++i)
            facc = fmaf(Wf_s[(D + i) * D + lane], readlane_f(kd, i), facc);
        const float f = tanhf(facc + bf_r);

        float c = f * wp_r;
        #pragma unroll
        for (int off = 32; off; off >>= 1) c += __shfl_xor(c, off, 64);
        if (lane == 0) out[b * L + l] = 1.f / (1.f + expf(-(c + bp_r)));
    }
}

extern "C" void kernel_launch(void* const* d_in, const int* in_sizes, int n_in,
                              void* d_out, int out_size, void* d_ws, size_t ws_size,
                              hipStream_t stream) {
    const int*   cseqs      = (const int*)d_in[0];
    const int*   rseqs      = (const int*)d_in[1];
    const int*   shft_cseqs = (const int*)d_in[2];
    const int*   shft_rseqs = (const int*)d_in[3];
    const float* kemb = (const float*)d_in[4];
    const float* vemb = (const float*)d_in[5];
    const float* Mk   = (const float*)d_in[6];
    const float* Mv0  = (const float*)d_in[7];
    const float* Wf   = (const float*)d_in[8];
    const float* bf   = (const float*)d_in[9];
    const float* We   = (const float*)d_in[10];
    const float* be   = (const float*)d_in[11];
    const float* Wa   = (const float*)d_in[12];
    const float* ba   = (const float*)d_in[13];
    const float* Wp   = (const float*)d_in[14];
    const float* bp   = (const float*)d_in[15];
    float* out = (float*)d_out;

    float* ws    = (float*)d_ws;
    float* ws_w  = ws;                        // B*L*M   = 640000 floats
    float* ws_e  = ws_w + (size_t)B * L * M;  // B*L*D   = 819200
    float* ws_a  = ws_e + (size_t)B * L * D;  // B*L*D
    float* ws_rp = ws_a + (size_t)B * L * D;  // NCH*B*L*D = 4096000
    // total: 25.5 MB of workspace

    phase1<<<dim3(800), dim3(256), 0, stream>>>(
        cseqs, rseqs, shft_cseqs, shft_rseqs, kemb, vemb,
        Mk, We, be, Wa, ba, ws_w, ws_e, ws_a);
    phase2<<<dim3(B * NCH), dim3(64), 0, stream>>>(Mv0, ws_w, ws_e, ws_a, ws_rp);
    phase3<<<dim3(800), dim3(512), 0, stream>>>(
        cseqs, shft_cseqs, kemb, Wf, bf, Wp, bp, ws_rp, out);
}

// Round 2
// 158.798 us; speedup vs baseline: 1.0909x; 1.0909x over previous
//
#include <hip/hip_runtime.h>
#include <hip/hip_bf16.h>
#include <math.h>

#define B    64
#define L1   199
#define L    200
#define NC   1000
#define D    64
#define M    50
#define NCH  10     // m-chunks in the scan
#define MC   5      // m per chunk (NCH*MC = M)
#define TCC  50     // time-chunk per scan stage (L/TCC = 4)

__device__ __forceinline__ float readlane_f(float v, int lane) {
    return __uint_as_float(__builtin_amdgcn_readlane(__float_as_uint(v), lane));
}

// ---------------- Phase 1: w = softmax(k@Mk^T), e = sigmoid(v@We+be), a = tanh(v@Wa+ba)
// 400 blocks x 256; weights register-resident; each wave does 8 positions
__global__ __launch_bounds__(256, 1) void phase1(
    const int* __restrict__ cseqs, const int* __restrict__ rseqs,
    const int* __restrict__ shft_cseqs, const int* __restrict__ shft_rseqs,
    const float* __restrict__ kemb, const float* __restrict__ vemb,
    const float* __restrict__ Mk, const float* __restrict__ We,
    const float* __restrict__ be, const float* __restrict__ Wa,
    const float* __restrict__ ba,
    float* __restrict__ w_out, float* __restrict__ e_out, float* __restrict__ a_out)
{
    const int tid  = threadIdx.x;
    const int lane = tid & 63;
    const int wave = tid >> 6;

    // Mk row (lane = m, clamped), in registers
    float Mk_r[D];
    {
        const int mrow = (lane < M) ? lane : (M - 1);
        #pragma unroll
        for (int d = 0; d < D; d += 4) {
            const float4 t4 = *(const float4*)(Mk + mrow * D + d);
            Mk_r[d] = t4.x; Mk_r[d + 1] = t4.y; Mk_r[d + 2] = t4.z; Mk_r[d + 3] = t4.w;
        }
    }
    // We/Wa columns (lane = d_out), in registers — coalesced loads
    float We_c[D], Wa_c[D];
    #pragma unroll
    for (int din = 0; din < D; ++din) {
        We_c[din] = We[din * D + lane];
        Wa_c[din] = Wa[din * D + lane];
    }
    const float be_r = be[lane];
    const float ba_r = ba[lane];

    #pragma unroll 1
    for (int p = 0; p < 8; ++p) {
        const int gpos = blockIdx.x * 32 + wave * 8 + p;   // 400*32 = 12800 = B*L
        const int b = gpos / L, l = gpos % L;
        int q, r;
        if (l == 0) { q = cseqs[b * L1];              r = rseqs[b * L1]; }
        else        { q = shft_cseqs[b * L1 + l - 1]; r = shft_rseqs[b * L1 + l - 1]; }
        const int x = q + NC * r;
        const float kd = kemb[q * D + lane];
        const float vd = vemb[x * D + lane];

        // logits over m (lane = m); k[d] broadcast via readlane; 2 accumulators
        float a0 = 0.f, a1 = 0.f;
        #pragma unroll
        for (int d = 0; d < D; d += 2) {
            a0 = fmaf(Mk_r[d],     readlane_f(kd, d),     a0);
            a1 = fmaf(Mk_r[d + 1], readlane_f(kd, d + 1), a1);
        }
        const float logit = (lane < M) ? (a0 + a1) : -INFINITY;
        float mx = logit;
        #pragma unroll
        for (int off = 32; off; off >>= 1) mx = fmaxf(mx, __shfl_xor(mx, off, 64));
        const float ex = expf(logit - mx);
        float sm = ex;
        #pragma unroll
        for (int off = 32; off; off >>= 1) sm += __shfl_xor(sm, off, 64);
        if (lane < M) w_out[gpos * M + lane] = ex / sm;

        // e, a (lane = d_out); v[d_in] broadcast via readlane
        float acce = 0.f, acca = 0.f;
        #pragma unroll
        for (int din = 0; din < D; ++din) {
            const float sv = readlane_f(vd, din);
            acce = fmaf(We_c[din], sv, acce);
            acca = fmaf(Wa_c[din], sv, acca);
        }
        e_out[gpos * D + lane] = 1.f / (1.f + expf(-(acce + be_r)));
        a_out[gpos * D + lane] = tanhf(acca + ba_r);
    }
}

// ---------------- Phase 2: the scan. One single-wave block per (b, m-chunk).
// lane = d; Mv[MC] in registers; w in registers via readlane; e/a LDS-staged + prefetched.
__global__ __launch_bounds__(64) void phase2(
    const float* __restrict__ Mv0,
    const float* __restrict__ w_in, const float* __restrict__ e_in,
    const float* __restrict__ a_in, float* __restrict__ rp_out)
{
    __shared__ float es[TCC * D];
    __shared__ float as_[TCC * D];
    const int lane = threadIdx.x;
    const int b  = blockIdx.x / NCH;
    const int ch = blockIdx.x % NCH;
    const int m0 = ch * MC;

    float Mv[MC];
    #pragma unroll
    for (int j = 0; j < MC; ++j) Mv[j] = Mv0[(m0 + j) * D + lane];

    float* rpb = rp_out + ((size_t)ch * B + b) * L * D;

    for (int tcb = 0; tcb < L / TCC; ++tcb) {
        const int t0 = tcb * TCC;
        // stage e/a time-chunk into LDS (bulk float4, coalesced): 800 float4 each
        {
            const float4* se = (const float4*)(e_in + (size_t)(b * L + t0) * D);
            const float4* sa = (const float4*)(a_in + (size_t)(b * L + t0) * D);
            float4* de = (float4*)es;
            float4* da = (float4*)as_;
            #pragma unroll
            for (int i = 0; i < 12; ++i) {
                de[lane + 64 * i] = se[lane + 64 * i];
                da[lane + 64 * i] = sa[lane + 64 * i];
            }
            if (lane < 32) { de[lane + 768] = se[lane + 768]; da[lane + 768] = sa[lane + 768]; }
        }
        // w time-chunk into registers: lane tl holds w[t0+tl][m0+j] (clamped, no divergence)
        float wreg[MC];
        {
            const int tl = (lane < TCC) ? lane : (TCC - 1);
            const float* wp = w_in + (size_t)(b * L + t0 + tl) * M + m0;
            #pragma unroll
            for (int j = 0; j < MC; ++j) wreg[j] = wp[j];
        }
        __syncthreads();

        float ed = es[lane], ad = as_[lane];
        for (int t = 0; t < TCC; ++t) {
            float edn = 0.f, adn = 0.f;
            if (t + 1 < TCC) { edn = es[(t + 1) * D + lane]; adn = as_[(t + 1) * D + lane]; }
            float r0 = 0.f, r1 = 0.f;
            #pragma unroll
            for (int j = 0; j < MC; ++j) {
                const float wm = readlane_f(wreg[j], t);   // uniform SGPR index
                if (j & 1) r1 = fmaf(wm, Mv[j], r1);
                else       r0 = fmaf(wm, Mv[j], r0);       // read BEFORE update
                const float we = wm * ed;
                Mv[j] = fmaf(Mv[j], -we, fmaf(wm, ad, Mv[j]));  // Mv*(1-we) + wm*ad
            }
            rpb[(t0 + t) * D + lane] = r0 + r1;
            ed = edn; ad = adn;
        }
        __syncthreads();
    }
}

// ---------------- Phase 3: read = sum partials; f = tanh([read,k]@Wf+bf); p = sigmoid(f@Wp+bp)
// 400 blocks x 256; Wf register-resident; each wave does 8 positions
__global__ __launch_bounds__(256, 1) void phase3(
    const int* __restrict__ cseqs, const int* __restrict__ shft_cseqs,
    const float* __restrict__ kemb,
    const float* __restrict__ Wf, const float* __restrict__ bf,
    const float* __restrict__ Wp, const float* __restrict__ bp,
    const float* __restrict__ rp, float* __restrict__ out)
{
    const int tid  = threadIdx.x;
    const int lane = tid & 63;
    const int wave = tid >> 6;

    // Wf columns (lane = d_out): 128 registers
    float Wf_c[2 * D];
    #pragma unroll
    for (int i = 0; i < 2 * D; ++i) Wf_c[i] = Wf[i * D + lane];
    const float bf_r = bf[lane];
    const float wp_r = Wp[lane];
    const float bp_r = bp[0];

    #pragma unroll 1
    for (int p = 0; p < 8; ++p) {
        const int gpos = blockIdx.x * 32 + wave * 8 + p;   // 400*32 = 12800
        const int b = gpos / L, l = gpos % L;
        float rd = 0.f;
        #pragma unroll
        for (int ch = 0; ch < NCH; ++ch)
            rd += rp[(((size_t)ch * B + b) * L + l) * D + lane];
        const int q = (l == 0) ? cseqs[b * L1] : shft_cseqs[b * L1 + l - 1];
        const float kd = kemb[q * D + lane];

        float f0 = 0.f, f1 = 0.f;
        #pragma unroll
        for (int i = 0; i < D; ++i) {
            f0 = fmaf(Wf_c[i],     readlane_f(rd, i), f0);
            f1 = fmaf(Wf_c[D + i], readlane_f(kd, i), f1);
        }
        const float f = tanhf(f0 + f1 + bf_r);

        float c = f * wp_r;
        #pragma unroll
        for (int off = 32; off; off >>= 1) c += __shfl_xor(c, off, 64);
        if (lane == 0) out[b * L + l] = 1.f / (1.f + expf(-(c + bp_r)));
    }
}

extern "C" void kernel_launch(void* const* d_in, const int* in_sizes, int n_in,
                              void* d_out, int out_size, void* d_ws, size_t ws_size,
                              hipStream_t stream) {
    const int*   cseqs      = (const int*)d_in[0];
    const int*   rseqs      = (const int*)d_in[1];
    const int*   shft_cseqs = (const int*)d_in[2];
    const int*   shft_rseqs = (const int*)d_in[3];
    const float* kemb = (const float*)d_in[4];
    const float* vemb = (const float*)d_in[5];
    const float* Mk   = (const float*)d_in[6];
    const float* Mv0  = (const float*)d_in[7];
    const float* Wf   = (const float*)d_in[8];
    const float* bf   = (const float*)d_in[9];
    const float* We   = (const float*)d_in[10];
    const float* be   = (const float*)d_in[11];
    const float* Wa   = (const float*)d_in[12];
    const float* ba   = (const float*)d_in[13];
    const float* Wp   = (const float*)d_in[14];
    const float* bp   = (const float*)d_in[15];
    float* out = (float*)d_out;

    float* ws    = (float*)d_ws;
    float* ws_w  = ws;                        // B*L*M     =   640000 floats
    float* ws_e  = ws_w + (size_t)B * L * M;  // B*L*D     =   819200
    float* ws_a  = ws_e + (size_t)B * L * D;  // B*L*D     =   819200
    float* ws_rp = ws_a + (size_t)B * L * D;  // NCH*B*L*D =  8192000
    // total ~41.9 MB of workspace

    phase1<<<dim3(400), dim3(256), 0, stream>>>(
        cseqs, rseqs, shft_cseqs, shft_rseqs, kemb, vemb,
        Mk, We, be, Wa, ba, ws_w, ws_e, ws_a);
    phase2<<<dim3(B * NCH), dim3(64), 0, stream>>>(Mv0, ws_w, ws_e, ws_a, ws_rp);
    phase3<<<dim3(400), dim3(256), 0, stream>>>(
        cseqs, shft_cseqs, kemb, Wf, bf, Wp, bp, ws_rp, out);
}

// Round 3
// 144.911 us; speedup vs baseline: 1.1954x; 1.0958x over previous
//
#include <hip/hip_runtime.h>
#include <hip/hip_bf16.h>
#include <math.h>

#define B    64
#define L1   199
#define L    200
#define NC   1000
#define D    64
#define M    50
#define NCH  10     // m-chunks in the scan
#define MC   5      // m per chunk (NCH*MC = M)
#define TCC  50     // time-chunk per scan stage (L/TCC = 4)

__device__ __forceinline__ float readlane_f(float v, int lane) {
    return __uint_as_float(__builtin_amdgcn_readlane(__float_as_uint(v), lane));
}

// ---------------- Phase 1: w = softmax(k@Mk^T), e = sigmoid(v@We+be), a = tanh(v@Wa+ba)
// 400 blocks x 256; weights register-resident; each wave does 8 positions.
// Gathers for all 8 positions prefetched upfront (indices are wave-uniform -> s_loads).
__global__ __launch_bounds__(256, 1) void phase1(
    const int* __restrict__ cseqs, const int* __restrict__ rseqs,
    const int* __restrict__ shft_cseqs, const int* __restrict__ shft_rseqs,
    const float* __restrict__ kemb, const float* __restrict__ vemb,
    const float* __restrict__ Mk, const float* __restrict__ We,
    const float* __restrict__ be, const float* __restrict__ Wa,
    const float* __restrict__ ba,
    float* __restrict__ w_out, float* __restrict__ e_out, float* __restrict__ a_out)
{
    const int tid  = threadIdx.x;
    const int lane = tid & 63;
    const int wave = tid >> 6;

    // Mk row (lane = m, clamped)
    float Mk_r[D];
    {
        const int mrow = (lane < M) ? lane : (M - 1);
        #pragma unroll
        for (int d = 0; d < D; d += 4) {
            const float4 t4 = *(const float4*)(Mk + mrow * D + d);
            Mk_r[d] = t4.x; Mk_r[d + 1] = t4.y; Mk_r[d + 2] = t4.z; Mk_r[d + 3] = t4.w;
        }
    }
    // We/Wa columns (lane = d_out) — coalesced
    float We_c[D], Wa_c[D];
    #pragma unroll
    for (int din = 0; din < D; ++din) {
        We_c[din] = We[din * D + lane];
        Wa_c[din] = Wa[din * D + lane];
    }
    const float be_r = be[lane];
    const float ba_r = ba[lane];

    const int base = blockIdx.x * 32 + wave * 8;   // 400*32 = 12800 = B*L

    // prefetch embeddings for all 8 positions (independent loads, one wait)
    float kd[8], vd[8];
    #pragma unroll
    for (int p = 0; p < 8; ++p) {
        const int gpos = base + p;
        const int b = gpos / L, l = gpos % L;
        int q, r;
        if (l == 0) { q = cseqs[b * L1];              r = rseqs[b * L1]; }
        else        { q = shft_cseqs[b * L1 + l - 1]; r = shft_rseqs[b * L1 + l - 1]; }
        kd[p] = kemb[q * D + lane];
        vd[p] = vemb[(q + NC * r) * D + lane];
    }

    #pragma unroll
    for (int p = 0; p < 8; ++p) {
        const int gpos = base + p;
        // logits over m (lane = m); k[d] broadcast via readlane
        float a0 = 0.f, a1 = 0.f;
        #pragma unroll
        for (int d = 0; d < D; d += 2) {
            a0 = fmaf(Mk_r[d],     readlane_f(kd[p], d),     a0);
            a1 = fmaf(Mk_r[d + 1], readlane_f(kd[p], d + 1), a1);
        }
        const float logit = (lane < M) ? (a0 + a1) : -INFINITY;
        float mx = logit;
        #pragma unroll
        for (int off = 32; off; off >>= 1) mx = fmaxf(mx, __shfl_xor(mx, off, 64));
        const float ex = expf(logit - mx);
        float sm = ex;
        #pragma unroll
        for (int off = 32; off; off >>= 1) sm += __shfl_xor(sm, off, 64);
        if (lane < M) w_out[gpos * M + lane] = ex / sm;

        // e, a (lane = d_out); v[d_in] broadcast via readlane (shared between both)
        float acce = 0.f, acca = 0.f;
        #pragma unroll
        for (int din = 0; din < D; ++din) {
            const float sv = readlane_f(vd[p], din);
            acce = fmaf(We_c[din], sv, acce);
            acca = fmaf(Wa_c[din], sv, acca);
        }
        e_out[gpos * D + lane] = 1.f / (1.f + expf(-(acce + be_r)));
        a_out[gpos * D + lane] = tanhf(acca + ba_r);
    }
}

// ---------------- Phase 2: the scan. One single-wave block per (b, m-chunk).
// lane = d. EVERYTHING in registers: Mv[MC], w via readlane, e/a as er/ar[TCC]
// (fully-unrolled t-loop so all array indices are static). No LDS, no barriers.
__global__ __launch_bounds__(64) void phase2(
    const float* __restrict__ Mv0,
    const float* __restrict__ w_in, const float* __restrict__ e_in,
    const float* __restrict__ a_in, float* __restrict__ rp_out)
{
    const int lane = threadIdx.x;
    const int b  = blockIdx.x / NCH;
    const int ch = blockIdx.x % NCH;
    const int m0 = ch * MC;

    float Mv[MC];
    #pragma unroll
    for (int j = 0; j < MC; ++j) Mv[j] = Mv0[(m0 + j) * D + lane];

    const float* eb = e_in + (size_t)b * L * D + lane;
    const float* ab = a_in + (size_t)b * L * D + lane;

    for (int tcb = 0; tcb < L / TCC; ++tcb) {
        const int t0 = tcb * TCC;

        // e/a time-chunk into registers (100 independent coalesced loads)
        float er[TCC], ar[TCC];
        #pragma unroll
        for (int t = 0; t < TCC; ++t) {
            er[t] = eb[(t0 + t) * D];
            ar[t] = ab[(t0 + t) * D];
        }
        // w time-chunk into registers: lane tl holds w[t0+tl][m0+j]
        float wreg[MC];
        {
            const int tl = (lane < TCC) ? lane : (TCC - 1);
            const float* wp = w_in + (size_t)(b * L + t0 + tl) * M + m0;
            #pragma unroll
            for (int j = 0; j < MC; ++j) wreg[j] = wp[j];
        }

        #pragma unroll
        for (int t = 0; t < TCC; ++t) {
            const float ed = er[t], ad = ar[t];
            float r0 = 0.f, r1 = 0.f;
            #pragma unroll
            for (int j = 0; j < MC; ++j) {
                const float wm = readlane_f(wreg[j], t);   // static lane index
                if (j & 1) r1 = fmaf(wm, Mv[j], r1);
                else       r0 = fmaf(wm, Mv[j], r0);       // read BEFORE update
                const float we = wm * ed;
                Mv[j] = fmaf(Mv[j], -we, fmaf(wm, ad, Mv[j]));  // Mv*(1-we) + wm*ad
            }
            // rp layout [b][t][ch][d]
            rp_out[(((size_t)b * L + t0 + t) * NCH + ch) * D + lane] = r0 + r1;
        }
    }
}

// ---------------- Phase 3: read = sum partials; f = tanh([read,k]@Wf+bf); p = sigmoid(f@Wp+bp)
// 400 blocks x 256; Wf register-resident; each wave does 8 positions; q prefetched.
__global__ __launch_bounds__(256, 1) void phase3(
    const int* __restrict__ cseqs, const int* __restrict__ shft_cseqs,
    const float* __restrict__ kemb,
    const float* __restrict__ Wf, const float* __restrict__ bf,
    const float* __restrict__ Wp, const float* __restrict__ bp,
    const float* __restrict__ rp, float* __restrict__ out)
{
    const int tid  = threadIdx.x;
    const int lane = tid & 63;
    const int wave = tid >> 6;

    float Wf_c[2 * D];
    #pragma unroll
    for (int i = 0; i < 2 * D; ++i) Wf_c[i] = Wf[i * D + lane];
    const float bf_r = bf[lane];
    const float wp_r = Wp[lane];
    const float bp_r = bp[0];

    const int base = blockIdx.x * 32 + wave * 8;   // 400*32 = 12800

    int q8[8];
    #pragma unroll
    for (int p = 0; p < 8; ++p) {
        const int gpos = base + p;
        const int b = gpos / L, l = gpos % L;
        q8[p] = (l == 0) ? cseqs[b * L1] : shft_cseqs[b * L1 + l - 1];
    }

    #pragma unroll 2
    for (int p = 0; p < 8; ++p) {
        const int gpos = base + p;
        const float kd = kemb[q8[p] * D + lane];
        float rd = 0.f;
        #pragma unroll
        for (int ch = 0; ch < NCH; ++ch)
            rd += rp[((size_t)gpos * NCH + ch) * D + lane];

        float f0 = 0.f, f1 = 0.f;
        #pragma unroll
        for (int i = 0; i < D; ++i) {
            f0 = fmaf(Wf_c[i],     readlane_f(rd, i), f0);
            f1 = fmaf(Wf_c[D + i], readlane_f(kd, i), f1);
        }
        const float f = tanhf(f0 + f1 + bf_r);

        float c = f * wp_r;
        #pragma unroll
        for (int off = 32; off; off >>= 1) c += __shfl_xor(c, off, 64);
        if (lane == 0) out[gpos] = 1.f / (1.f + expf(-(c + bp_r)));
    }
}

extern "C" void kernel_launch(void* const* d_in, const int* in_sizes, int n_in,
                              void* d_out, int out_size, void* d_ws, size_t ws_size,
                              hipStream_t stream) {
    const int*   cseqs      = (const int*)d_in[0];
    const int*   rseqs      = (const int*)d_in[1];
    const int*   shft_cseqs = (const int*)d_in[2];
    const int*   shft_rseqs = (const int*)d_in[3];
    const float* kemb = (const float*)d_in[4];
    const float* vemb = (const float*)d_in[5];
    const float* Mk   = (const float*)d_in[6];
    const float* Mv0  = (const float*)d_in[7];
    const float* Wf   = (const float*)d_in[8];
    const float* bf   = (const float*)d_in[9];
    const float* We   = (const float*)d_in[10];
    const float* be   = (const float*)d_in[11];
    const float* Wa   = (const float*)d_in[12];
    const float* ba   = (const float*)d_in[13];
    const float* Wp   = (const float*)d_in[14];
    const float* bp   = (const float*)d_in[15];
    float* out = (float*)d_out;

    float* ws    = (float*)d_ws;
    float* ws_w  = ws;                        // B*L*M       =   640000 floats
    float* ws_e  = ws_w + (size_t)B * L * M;  // B*L*D       =   819200
    float* ws_a  = ws_e + (size_t)B * L * D;  // B*L*D       =   819200
    float* ws_rp = ws_a + (size_t)B * L * D;  // B*L*NCH*D   =  8192000
    // total ~42 MB of workspace

    phase1<<<dim3(400), dim3(256), 0, stream>>>(
        cseqs, rseqs, shft_cseqs, shft_rseqs, kemb, vemb,
        Mk, We, be, Wa, ba, ws_w, ws_e, ws_a);
    phase2<<<dim3(B * NCH), dim3(64), 0, stream>>>(Mv0, ws_w, ws_e, ws_a, ws_rp);
    phase3<<<dim3(400), dim3(256), 0, stream>>>(
        cseqs, shft_cseqs, kemb, Wf, bf, Wp, bp, ws_rp, out);
}

// Round 4
// 144.497 us; speedup vs baseline: 1.1988x; 1.0029x over previous
//
#include <hip/hip_runtime.h>
#include <hip/hip_bf16.h>
#include <math.h>

#define B    64
#define L1   199
#define L    200
#define NC   1000
#define D    64
#define M    50
#define NCH  10     // m-chunks in the scan
#define MC   5      // m per chunk (NCH*MC = M)
#define TCC  50     // time-chunk per scan stage (L/TCC = 4)

__device__ __forceinline__ float readlane_f(float v, int lane) {
    return __uint_as_float(__builtin_amdgcn_readlane(__float_as_uint(v), lane));
}

// ---------------- Phase 1, role-split: 4800 single-wave blocks.
// role 0: w = softmax(k@Mk^T)   (holds Mk row only, 64 VGPR)
// role 1: e = sigmoid(v@We+be)  (holds We column only, 64 VGPR)
// role 2: a = tanh(v@Wa+ba)     (holds Wa column only, 64 VGPR)
// Each wave: 8 positions. 4800 waves = 4.7/SIMD -> latency hidden.
__global__ __launch_bounds__(64) void phase1(
    const int* __restrict__ cseqs, const int* __restrict__ rseqs,
    const int* __restrict__ shft_cseqs, const int* __restrict__ shft_rseqs,
    const float* __restrict__ kemb, const float* __restrict__ vemb,
    const float* __restrict__ Mk, const float* __restrict__ We,
    const float* __restrict__ be, const float* __restrict__ Wa,
    const float* __restrict__ ba,
    float* __restrict__ w_out, float* __restrict__ e_out, float* __restrict__ a_out)
{
    const int lane = threadIdx.x;
    const int bid  = blockIdx.x;
    const int role = bid % 3;        // 0=w, 1=e, 2=a
    const int base = (bid / 3) * 8;  // 1600 waves per role * 8 = 12800 positions

    // indices for all 8 positions (wave-uniform scalar loads)
    int q8[8], x8[8];
    #pragma unroll
    for (int p = 0; p < 8; ++p) {
        const int gpos = base + p;
        const int b = gpos / L, l = gpos % L;
        int q, r;
        if (l == 0) { q = cseqs[b * L1];              r = rseqs[b * L1]; }
        else        { q = shft_cseqs[b * L1 + l - 1]; r = shft_rseqs[b * L1 + l - 1]; }
        q8[p] = q; x8[p] = q + NC * r;
    }

    if (role != 0) {
        // ---- e or a: lane = d_out; weight column register-resident
        const float* __restrict__ W  = (role == 1) ? We : Wa;
        const float* __restrict__ bb = (role == 1) ? be : ba;
        float*       __restrict__ dst = (role == 1) ? e_out : a_out;

        float Wc[D];
        #pragma unroll
        for (int din = 0; din < D; ++din) Wc[din] = W[din * D + lane];
        const float br = bb[lane];

        float vd[8];
        #pragma unroll
        for (int p = 0; p < 8; ++p) vd[p] = vemb[(size_t)x8[p] * D + lane];

        #pragma unroll
        for (int p = 0; p < 8; ++p) {
            float c0 = 0.f, c1 = 0.f;
            #pragma unroll
            for (int din = 0; din < D; din += 2) {
                c0 = fmaf(Wc[din],     readlane_f(vd[p], din),     c0);
                c1 = fmaf(Wc[din + 1], readlane_f(vd[p], din + 1), c1);
            }
            const float acc = c0 + c1;
            const float r = (role == 1) ? (1.f / (1.f + expf(-(acc + br))))
                                        : tanhf(acc + br);
            dst[(size_t)(base + p) * D + lane] = r;
        }
    } else {
        // ---- w: lane = m; Mk row register-resident
        float Mk_r[D];
        {
            const int mrow = (lane < M) ? lane : (M - 1);
            #pragma unroll
            for (int d = 0; d < D; d += 4) {
                const float4 t4 = *(const float4*)(Mk + mrow * D + d);
                Mk_r[d] = t4.x; Mk_r[d+1] = t4.y; Mk_r[d+2] = t4.z; Mk_r[d+3] = t4.w;
            }
        }
        float kd[8];
        #pragma unroll
        for (int p = 0; p < 8; ++p) kd[p] = kemb[(size_t)q8[p] * D + lane];

        #pragma unroll
        for (int p = 0; p < 8; ++p) {
            float c0 = 0.f, c1 = 0.f;
            #pragma unroll
            for (int d = 0; d < D; d += 2) {
                c0 = fmaf(Mk_r[d],     readlane_f(kd[p], d),     c0);
                c1 = fmaf(Mk_r[d + 1], readlane_f(kd[p], d + 1), c1);
            }
            const float logit = (lane < M) ? (c0 + c1) : -INFINITY;
            float mx = logit;
            #pragma unroll
            for (int off = 32; off; off >>= 1) mx = fmaxf(mx, __shfl_xor(mx, off, 64));
            const float ex = expf(logit - mx);
            float sm = ex;
            #pragma unroll
            for (int off = 32; off; off >>= 1) sm += __shfl_xor(sm, off, 64);
            if (lane < M) w_out[(size_t)(base + p) * M + lane] = ex / sm;
        }
    }
}

// ---------------- Phase 2: the scan. One single-wave block per (b, m-chunk).
// lane = d. Everything in registers; no LDS, no barriers.
__global__ __launch_bounds__(64) void phase2(
    const float* __restrict__ Mv0,
    const float* __restrict__ w_in, const float* __restrict__ e_in,
    const float* __restrict__ a_in, float* __restrict__ rp_out)
{
    const int lane = threadIdx.x;
    const int b  = blockIdx.x / NCH;
    const int ch = blockIdx.x % NCH;
    const int m0 = ch * MC;

    float Mv[MC];
    #pragma unroll
    for (int j = 0; j < MC; ++j) Mv[j] = Mv0[(m0 + j) * D + lane];

    const float* eb = e_in + (size_t)b * L * D + lane;
    const float* ab = a_in + (size_t)b * L * D + lane;

    for (int tcb = 0; tcb < L / TCC; ++tcb) {
        const int t0 = tcb * TCC;

        float er[TCC], ar[TCC];
        #pragma unroll
        for (int t = 0; t < TCC; ++t) {
            er[t] = eb[(t0 + t) * D];
            ar[t] = ab[(t0 + t) * D];
        }
        float wreg[MC];
        {
            const int tl = (lane < TCC) ? lane : (TCC - 1);
            const float* wp = w_in + (size_t)(b * L + t0 + tl) * M + m0;
            #pragma unroll
            for (int j = 0; j < MC; ++j) wreg[j] = wp[j];
        }

        #pragma unroll
        for (int t = 0; t < TCC; ++t) {
            const float ed = er[t], ad = ar[t];
            float r0 = 0.f, r1 = 0.f;
            #pragma unroll
            for (int j = 0; j < MC; ++j) {
                const float wm = readlane_f(wreg[j], t);   // static lane index
                if (j & 1) r1 = fmaf(wm, Mv[j], r1);
                else       r0 = fmaf(wm, Mv[j], r0);       // read BEFORE update
                const float we = wm * ed;
                Mv[j] = fmaf(Mv[j], -we, fmaf(wm, ad, Mv[j]));  // Mv*(1-we) + wm*ad
            }
            rp_out[(((size_t)b * L + t0 + t) * NCH + ch) * D + lane] = r0 + r1;
        }
    }
}

// ---------------- Phase 3: read = sum partials; f = tanh([read,k]@Wf+bf); p = sigmoid(f@Wp+bp)
// 800 blocks x 256; Wf register-resident; 4 positions per wave (3200 waves).
__global__ __launch_bounds__(256, 1) void phase3(
    const int* __restrict__ cseqs, const int* __restrict__ shft_cseqs,
    const float* __restrict__ kemb,
    const float* __restrict__ Wf, const float* __restrict__ bf,
    const float* __restrict__ Wp, const float* __restrict__ bp,
    const float* __restrict__ rp, float* __restrict__ out)
{
    const int tid  = threadIdx.x;
    const int lane = tid & 63;
    const int wave = tid >> 6;

    float Wf_c[2 * D];
    #pragma unroll
    for (int i = 0; i < 2 * D; ++i) Wf_c[i] = Wf[i * D + lane];
    const float bf_r = bf[lane];
    const float wp_r = Wp[lane];
    const float bp_r = bp[0];

    const int base = blockIdx.x * 16 + wave * 4;   // 800*16 = 12800

    int q4[4];
    #pragma unroll
    for (int p = 0; p < 4; ++p) {
        const int gpos = base + p;
        const int b = gpos / L, l = gpos % L;
        q4[p] = (l == 0) ? cseqs[b * L1] : shft_cseqs[b * L1 + l - 1];
    }

    #pragma unroll
    for (int p = 0; p < 4; ++p) {
        const int gpos = base + p;
        const float kd = kemb[(size_t)q4[p] * D + lane];
        float rd = 0.f;
        #pragma unroll
        for (int ch = 0; ch < NCH; ++ch)
            rd += rp[((size_t)gpos * NCH + ch) * D + lane];

        float f0 = 0.f, f1 = 0.f;
        #pragma unroll
        for (int i = 0; i < D; ++i) {
            f0 = fmaf(Wf_c[i],     readlane_f(rd, i), f0);
            f1 = fmaf(Wf_c[D + i], readlane_f(kd, i), f1);
        }
        const float f = tanhf(f0 + f1 + bf_r);

        float c = f * wp_r;
        #pragma unroll
        for (int off = 32; off; off >>= 1) c += __shfl_xor(c, off, 64);
        if (lane == 0) out[gpos] = 1.f / (1.f + expf(-(c + bp_r)));
    }
}

extern "C" void kernel_launch(void* const* d_in, const int* in_sizes, int n_in,
                              void* d_out, int out_size, void* d_ws, size_t ws_size,
                              hipStream_t stream) {
    const int*   cseqs      = (const int*)d_in[0];
    const int*   rseqs      = (const int*)d_in[1];
    const int*   shft_cseqs = (const int*)d_in[2];
    const int*   shft_rseqs = (const int*)d_in[3];
    const float* kemb = (const float*)d_in[4];
    const float* vemb = (const float*)d_in[5];
    const float* Mk   = (const float*)d_in[6];
    const float* Mv0  = (const float*)d_in[7];
    const float* Wf   = (const float*)d_in[8];
    const float* bf   = (const float*)d_in[9];
    const float* We   = (const float*)d_in[10];
    const float* be   = (const float*)d_in[11];
    const float* Wa   = (const float*)d_in[12];
    const float* ba   = (const float*)d_in[13];
    const float* Wp   = (const float*)d_in[14];
    const float* bp   = (const float*)d_in[15];
    float* out = (float*)d_out;

    float* ws    = (float*)d_ws;
    float* ws_w  = ws;                        // B*L*M       =   640000 floats
    float* ws_e  = ws_w + (size_t)B * L * M;  // B*L*D       =   819200
    float* ws_a  = ws_e + (size_t)B * L * D;  // B*L*D       =   819200
    float* ws_rp = ws_a + (size_t)B * L * D;  // B*L*NCH*D   =  8192000
    // total ~42 MB of workspace

    phase1<<<dim3(4800), dim3(64), 0, stream>>>(
        cseqs, rseqs, shft_cseqs, shft_rseqs, kemb, vemb,
        Mk, We, be, Wa, ba, ws_w, ws_e, ws_a);
    phase2<<<dim3(B * NCH), dim3(64), 0, stream>>>(Mv0, ws_w, ws_e, ws_a, ws_rp);
    phase3<<<dim3(800), dim3(256), 0, stream>>>(
        cseqs, shft_cseqs, kemb, Wf, bf, Wp, bp, ws_rp, out);
}